// Round 4
// baseline (38.654 us; speedup 1.0000x reference)
//
#include <hip/hip_runtime.h>

#define BINS 16
#define OUT_DIM 64
#define NB 64
#define NCH 3
#define NPIX (512 * 512)             // pixels per (b,c) plane
#define THREADS 256
#define CHUNK_PIX 8192               // pixels per task
#define TASKS_PER_PLANE (NPIX / CHUNK_PIX)        // 32
#define NTASKS (NB * NCH * TASKS_PER_PLANE)       // 6144
#define TASKS_PER_BLOCK 3
#define NBLOCKS (NTASKS / TASKS_PER_BLOCK)        // 2048 = 8 blocks/CU, fully resident
#define VEC_ITERS (CHUNK_PIX / 4 / THREADS)       // 8 float4 per thread per task
#define IN_DIM (NCH * BINS)                       // 48

typedef float f32x4 __attribute__((ext_vector_type(4)));   // native clang vector

// Kernel 1: 2048 blocks (exactly 32 waves/CU, single dispatch round, no tail).
// Each block processes 3 tasks of 8192 pixels into 3 separate LDS histograms,
// each replicated 64x (addr = bin*64 + lane -> bank = lane%32: only the free
// 2-way lane aliasing, zero same-address contention). Non-atomic partial store.
__global__ __launch_bounds__(THREADS) void hist_kernel(const float* __restrict__ x,
                                                       unsigned int* __restrict__ partials) {
    __shared__ unsigned int lh[TASKS_PER_BLOCK * BINS * 64];   // 12 KB
    for (int i = threadIdx.x; i < TASKS_PER_BLOCK * BINS * 64; i += THREADS) lh[i] = 0u;
    __syncthreads();

    const int lane = threadIdx.x & 63;

    #pragma unroll
    for (int j = 0; j < TASKS_PER_BLOCK; ++j) {
        const int task = blockIdx.x * TASKS_PER_BLOCK + j;
        const f32x4* __restrict__ src = (const f32x4*)(x + (size_t)task * CHUNK_PIX);
        unsigned int* h = &lh[j * BINS * 64];
        #pragma unroll
        for (int it = 0; it < VEC_ITERS; ++it) {
            f32x4 v = __builtin_nontemporal_load(&src[it * THREADS + threadIdx.x]);
            // x in [0,1): (int)(x*16.0f) == floor(x*16) exactly (mul by 2^4 exact).
            // min(15,.) guards an exact-1.0 input from an OOB LDS write.
            int i0 = min(BINS - 1, (int)(v.x * 16.0f));
            int i1 = min(BINS - 1, (int)(v.y * 16.0f));
            int i2 = min(BINS - 1, (int)(v.z * 16.0f));
            int i3 = min(BINS - 1, (int)(v.w * 16.0f));
            atomicAdd(&h[i0 * 64 + lane], 1u);
            atomicAdd(&h[i1 * 64 + lane], 1u);
            atomicAdd(&h[i2 * 64 + lane], 1u);
            atomicAdd(&h[i3 * 64 + lane], 1u);
        }
    }
    __syncthreads();

    // 48 threads: task-slot j = t/16, bin = t%16; sum the 64 lane copies.
    if (threadIdx.x < TASKS_PER_BLOCK * BINS) {
        const int j = threadIdx.x >> 4, bin = threadIdx.x & 15;
        unsigned int s = 0;
        #pragma unroll
        for (int k = 0; k < 64; ++k) s += lh[(j * BINS + bin) * 64 + k];
        partials[(size_t)(blockIdx.x * TASKS_PER_BLOCK + j) * BINS + bin] = s;
    }
}

// Kernel 2: one block per batch b. partials layout [plane][task][bin] with
// plane = b*3 + c, 32 tasks/plane. Reduce -> feat[48] -> FC + ReLU.
__global__ __launch_bounds__(256) void fc_kernel(const unsigned int* __restrict__ partials,
                                                 const float* __restrict__ fc_w,
                                                 const float* __restrict__ fc_b,
                                                 float* __restrict__ out) {
    __shared__ unsigned int tmp[NCH * TASKS_PER_PLANE * BINS];  // 1536
    __shared__ float feat[IN_DIM];
    const int b = blockIdx.x;
    const int tid = threadIdx.x;

    const unsigned int* src = partials + (size_t)b * NCH * TASKS_PER_PLANE * BINS;
    #pragma unroll
    for (int i = tid; i < NCH * TASKS_PER_PLANE * BINS; i += 256) tmp[i] = src[i];
    __syncthreads();

    if (tid < IN_DIM) {                      // t = c*16 + bin
        const int c = tid >> 4, bin = tid & 15;
        unsigned int s = 0;
        #pragma unroll
        for (int t = 0; t < TASKS_PER_PLANE; ++t)
            s += tmp[(c * TASKS_PER_PLANE + t) * BINS + bin];
        feat[tid] = (float)s * (1.0f / (float)NPIX);   // exact pow2 divide
    }
    __syncthreads();

    if (tid < OUT_DIM) {
        float s = fc_b[tid];
        #pragma unroll
        for (int k = 0; k < IN_DIM; ++k)
            s = fmaf(feat[k], fc_w[tid * IN_DIM + k], s);
        out[b * OUT_DIM + tid] = fmaxf(s, 0.0f);
    }
}

extern "C" void kernel_launch(void* const* d_in, const int* in_sizes, int n_in,
                              void* d_out, int out_size, void* d_ws, size_t ws_size,
                              hipStream_t stream) {
    const float* x    = (const float*)d_in[0];
    const float* fc_w = (const float*)d_in[1];
    const float* fc_b = (const float*)d_in[2];
    float* out = (float*)d_out;
    unsigned int* partials = (unsigned int*)d_ws;  // [6144 tasks][16 bins] = 393 KB

    hist_kernel<<<NBLOCKS, THREADS, 0, stream>>>(x, partials);
    fc_kernel<<<NB, 256, 0, stream>>>(partials, fc_w, fc_b, out);
}